// Round 22
// baseline (96.126 us; speedup 1.0000x reference)
//
#include <hip/hip_runtime.h>
#include <hip/hip_bf16.h>

#define ALPHA 0.2f
static __device__ __forceinline__ float lrel(float x) { return fmaxf(x, ALPHA * x); }

typedef __attribute__((ext_vector_type(8))) short bf16x8;
typedef __attribute__((ext_vector_type(4))) float f32x4;

union FragU { bf16x8 v; unsigned int u[4]; uint4 q; };

// VGPR-form MFMA via inline asm ("v" pins operands to arch VGPRs)
static __device__ __forceinline__ f32x4 mfma_init(bf16x8 a, bf16x8 b, f32x4 c) {
    f32x4 d;
    asm("v_mfma_f32_16x16x32_bf16 %0, %1, %2, %3" : "=&v"(d) : "v"(a), "v"(b), "v"(c));
    return d;
}
static __device__ __forceinline__ void mfma_acc(f32x4& acc, bf16x8 a, bf16x8 b) {
    asm("v_mfma_f32_16x16x32_bf16 %0, %1, %2, %0" : "+v"(acc) : "v"(a), "v"(b));
}

// pack two f32 -> one dword of 2 bf16 (RNE)
static __device__ __forceinline__ unsigned int pk2(float a, float b) {
    unsigned int r;
    asm("v_cvt_pk_bf16_f32 %0, %1, %2" : "=v"(r) : "v"(a), "v"(b));
    return r;
}
static __device__ __forceinline__ unsigned int cvl2(float a, float b) {
    return pk2(lrel(a), lrel(b));
}
// a += |x|  (VOP3 abs input modifier: single v_add)
static __device__ __forceinline__ void addabs(float& a, float x) {
    asm("v_add_f32 %0, %0, |%1|" : "+v"(a) : "v"(x));
}
// f32 -> bf16 (RNE) scalar
static __device__ __forceinline__ unsigned short f2bf(float x) {
    union { float f; unsigned int u; } c;
    c.f = x;
    unsigned int r = c.u + 0x7FFFu + ((c.u >> 16) & 1u);
    return (unsigned short)(r >> 16);
}
// pi permutation on 64 features: slot(16nf+4a+r) -> 32(nf>>1)+8a+4(nf&1)+r
static __device__ __forceinline__ int pi64(int s) {
    return 32 * ((s >> 4) >> 1) + 8 * ((s >> 2) & 3) + 4 * ((s >> 4) & 1) + (s & 3);
}

// ---------------- Kernel 1: Upi, x_bf, edge-weight fragments, fn-weight transpose ----------------
__global__ __launch_bounds__(256) void k_uv(
    const float* __restrict__ x, const float* __restrict__ W0, const float* __restrict__ b0,
    const float* __restrict__ W1, const float* __restrict__ W2,
    const float* __restrict__ fW0, const float* __restrict__ fW1, const float* __restrict__ fW2,
    float* __restrict__ Upi, unsigned short* __restrict__ xbf, unsigned int* __restrict__ WF,
    float* __restrict__ fWT)
{
    if (blockIdx.x == 1024) {
        const int t = threadIdx.x;
        const int l = t & 63, part = t >> 6;
        const int lo = l & 15, g = l >> 4;
        for (int ff = part; ff < 20; ff += 4) {
            unsigned int o[4];
            if (ff < 4) {
                const int nf = ff;
                const int pc = 32 * (nf >> 1) + 8 * (lo >> 2) + 4 * (nf & 1) + (lo & 3);
#pragma unroll
                for (int uq = 0; uq < 4; ++uq) {
                    const int k0 = 8 * g + 2 * uq;
                    o[uq] = pk2(W0[(32 + k0) * 64 + pc], W0[(33 + k0) * 64 + pc]);
                }
            } else if (ff < 12) {
                const int s = (ff - 4) >> 2, nf = (ff - 4) & 3;
                const int pc = 32 * (nf >> 1) + 8 * (lo >> 2) + 4 * (nf & 1) + (lo & 3);
#pragma unroll
                for (int uq = 0; uq < 4; ++uq) {
                    const int k0 = 32 * s + 8 * g + 2 * uq;
                    o[uq] = pk2(W1[k0 * 64 + pc], W1[(k0 + 1) * 64 + pc]);
                }
            } else {
                const int s = (ff - 12) >> 2, nf = (ff - 12) & 3;
                const int c2 = 16 * nf + lo;
#pragma unroll
                for (int uq = 0; uq < 4; ++uq) {
                    const int k0 = 32 * s + 8 * g + 2 * uq;
                    o[uq] = pk2(W2[k0 * 64 + c2], W2[(k0 + 1) * 64 + c2]);
                }
            }
            *(uint4*)(WF + (ff * 64 + l) * 4) = make_uint4(o[0], o[1], o[2], o[3]);
        }
        return;
    }
    if (blockIdx.x == 1025) {
        // transpose fn weights: fWT layout = fW0T[128][96] | fW1T[128][128] | fW2T[32][128]
        const int t = threadIdx.x;
        float* fW0T = fWT;
        float* fW1T = fWT + 12288;
        float* fW2T = fW1T + 16384;
        for (int idx = t; idx < 12288; idx += 256) {
            const int f = idx / 96, k = idx - f * 96;
            fW0T[idx] = fW0[k * 128 + f];
        }
        for (int idx = t; idx < 16384; idx += 256) {
            const int f = idx >> 7, k = idx & 127;
            fW1T[idx] = fW1[k * 128 + f];
        }
        for (int idx = t; idx < 4096; idx += 256) {
            const int fo = idx >> 7, k = idx & 127;
            fW2T[idx] = fW2[k * 32 + fo];
        }
        return;
    }
    const int idx = blockIdx.x * 256 + threadIdx.x;
    const int n = idx >> 6;
    const int slot = idx & 63;
    const int f = pi64(slot);
    const float* xr = x + n * 32;
    float u = b0[f];
#pragma unroll
    for (int i = 0; i < 32; ++i) u += xr[i] * W0[i * 64 + f];
    Upi[idx] = u;
    if (slot < 32) xbf[n * 32 + slot] = f2bf(xr[slot]);
}

// ---------------- Kernel 2: edge MLP (R15 verbatim — best measured) ----------------
__global__ __launch_bounds__(256, 2) void k_edge(
    const float* __restrict__ Upi, const unsigned short* __restrict__ xbf,
    const unsigned int* __restrict__ WF,
    const float* __restrict__ b1, const float* __restrict__ b2,
    float* __restrict__ AGG)
{
    __shared__ uint4 wlds[512];  // w1f frags only: [0..7] = (s*4+nf)
    const int tid = threadIdx.x;
    const int w = tid >> 6, l = tid & 63;
    const int lo = l & 15, g = l >> 4;
    const int bid = blockIdx.x;
    const int b = bid >> 7, ig = bid & 127;
    const int node = b * 512 + ig * 4 + w;

    // ---- stage W1 fragments into LDS (once per block)
    for (int idx = tid; idx < 512; idx += 256)
        wlds[idx] = ((const uint4*)WF)[256 + idx];

    // ---- W0bot + W2 fragments in registers
    FragU w0f[4], w2f[2][4];
    const uint4* wp = (const uint4*)WF;
#pragma unroll
    for (int nf = 0; nf < 4; ++nf) w0f[nf].q = wp[nf * 64 + l];
#pragma unroll
    for (int s = 0; s < 2; ++s)
#pragma unroll
        for (int nf = 0; nf < 4; ++nf) w2f[s][nf].q = wp[(12 + s * 4 + nf) * 64 + l];

    // ---- per-i C-init for GEMM0 (Upi broadcast) + bias C-inits
    f32x4 u0f[4], b1f[4], b2f[4];
#pragma unroll
    for (int nf = 0; nf < 4; ++nf) {
        const float4 t0 = *(const float4*)(Upi + node * 64 + nf * 16 + 4 * g);
        u0f[nf] = (f32x4){t0.x, t0.y, t0.z, t0.w};
        const float4 t1 = *(const float4*)(b1 + 32 * (nf >> 1) + 8 * g + 4 * (nf & 1));
        const float4 t2 = *(const float4*)(b2 + 16 * nf + 4 * g);
        b1f[nf] = (f32x4){t1.x, t1.y, t1.z, t1.w};
        b2f[nf] = (f32x4){t2.x, t2.y, t2.z, t2.w};
    }

    const unsigned short* xb = xbf + b * 512 * 32;

    // ---- prologue: xj frags for tiles 0,1; GEMM0 for tile 0
    FragU xjT0, xjB;
    xjT0.q = *(const uint4*)(xb + lo * 32 + 8 * g);         // tile 0
    xjB.q  = *(const uint4*)(xb + (16 + lo) * 32 + 8 * g);  // tile 1

    __syncthreads();

    f32x4 acc0c[4];
#pragma unroll
    for (int nf = 0; nf < 4; ++nf)
        acc0c[nf] = mfma_init(w0f[nf].v, xjT0.v, u0f[nf]);

    f32x4 acc2p[4];
#pragma unroll
    for (int nf = 0; nf < 4; ++nf) { f32x4 z = {0.f, 0.f, 0.f, 0.f}; acc2p[nf] = z; }

    float aggL[4][4], aggA[4][4];
#pragma unroll
    for (int nf = 0; nf < 4; ++nf)
#pragma unroll
        for (int r = 0; r < 4; ++r) { aggL[nf][r] = 0.f; aggA[nf][r] = 0.f; }

#pragma unroll 2
    for (int k = 0; k < 32; ++k) {
        // opaque zero: defeats LICM on the LDS weight reads
        int widx = 0;
        asm volatile("" : "+v"(widx));

        // load xj for tile k+2 (wraps; garbage tile never aggregated)
        const int jn = ((k + 2) & 31) * 16;
        FragU xjn;
        xjn.q = *(const uint4*)(xb + (jn + lo) * 32 + 8 * g);

        // ---- GEMM0 for tile k+1 (skewed one tile ahead)
        __builtin_amdgcn_s_setprio(1);
        f32x4 acc0n[4];
#pragma unroll
        for (int nf = 0; nf < 4; ++nf)
            acc0n[nf] = mfma_init(w0f[nf].v, xjB.v, u0f[nf]);
        __builtin_amdgcn_s_setprio(0);

        // ---- pack q from tile k's acc0 (overlaps GEMM0 MFMAs)
        FragU q0, q1;
        q0.u[0] = cvl2(acc0c[0][0], acc0c[0][1]);
        q0.u[1] = cvl2(acc0c[0][2], acc0c[0][3]);
        q0.u[2] = cvl2(acc0c[1][0], acc0c[1][1]);
        q0.u[3] = cvl2(acc0c[1][2], acc0c[1][3]);
        q1.u[0] = cvl2(acc0c[2][0], acc0c[2][1]);
        q1.u[1] = cvl2(acc0c[2][2], acc0c[2][3]);
        q1.u[2] = cvl2(acc0c[3][0], acc0c[3][1]);
        q1.u[3] = cvl2(acc0c[3][2], acc0c[3][3]);

        // ---- GEMM1 (W1 from LDS, bias C-init)
        __builtin_amdgcn_s_setprio(1);
        f32x4 acc1[4];
#pragma unroll
        for (int nf = 0; nf < 4; ++nf) {
            FragU wa, wb;
            wa.q = wlds[widx + nf * 64 + l];
            wb.q = wlds[widx + (4 + nf) * 64 + l];
            acc1[nf] = mfma_init(wa.v, q0.v, b1f[nf]);
            mfma_acc(acc1[nf], wb.v, q1.v);
        }
        __builtin_amdgcn_s_setprio(0);

        // ---- agg of PREVIOUS tile's acc2 (overlaps GEMM1 MFMAs)
#pragma unroll
        for (int nf = 0; nf < 4; ++nf)
#pragma unroll
            for (int r = 0; r < 4; ++r) {
                aggL[nf][r] += acc2p[nf][r];
                addabs(aggA[nf][r], acc2p[nf][r]);
            }

        // ---- pack p from acc1 (pi trick: regs are GEMM2's B-fragment)
        FragU p0, p1;
        p0.u[0] = cvl2(acc1[0][0], acc1[0][1]);
        p0.u[1] = cvl2(acc1[0][2], acc1[0][3]);
        p0.u[2] = cvl2(acc1[1][0], acc1[1][1]);
        p0.u[3] = cvl2(acc1[1][2], acc1[1][3]);
        p1.u[0] = cvl2(acc1[2][0], acc1[2][1]);
        p1.u[1] = cvl2(acc1[2][2], acc1[2][3]);
        p1.u[2] = cvl2(acc1[3][0], acc1[3][1]);
        p1.u[3] = cvl2(acc1[3][2], acc1[3][3]);

        // ---- GEMM2 (W2 in regs, bias C-init) -> becomes "previous" for next iter
        __builtin_amdgcn_s_setprio(1);
#pragma unroll
        for (int nf = 0; nf < 4; ++nf) {
            acc2p[nf] = mfma_init(w2f[0][nf].v, p0.v, b2f[nf]);
            mfma_acc(acc2p[nf], w2f[1][nf].v, p1.v);
        }
        __builtin_amdgcn_s_setprio(0);

        // ---- rotate skew buffers (unroll-2 ping-pongs, no copies)
#pragma unroll
        for (int nf = 0; nf < 4; ++nf) acc0c[nf] = acc0n[nf];
        xjB = xjn;
    }

    // ---- epilogue: agg the last tile's acc2
#pragma unroll
    for (int nf = 0; nf < 4; ++nf)
#pragma unroll
        for (int r = 0; r < 4; ++r) {
            aggL[nf][r] += acc2p[nf][r];
            addabs(aggA[nf][r], acc2p[nf][r]);
        }

    // ---- combine lrel parts, reduce over the 16 edge-lanes, store
#pragma unroll
    for (int nf = 0; nf < 4; ++nf)
#pragma unroll
        for (int r = 0; r < 4; ++r) {
            float v = 0.6f * aggL[nf][r] + 0.4f * aggA[nf][r];
            v += __shfl_xor(v, 1);
            v += __shfl_xor(v, 2);
            v += __shfl_xor(v, 4);
            v += __shfl_xor(v, 8);
            aggL[nf][r] = v;
        }
    if (lo == 0) {
#pragma unroll
        for (int nf = 0; nf < 4; ++nf) {
            float4 o = {aggL[nf][0], aggL[nf][1], aggL[nf][2], aggL[nf][3]};
            *(float4*)(AGG + node * 64 + 16 * nf + 4 * g) = o;
        }
    }
}

// ---------------- Kernel 3: node MLP with transposed weights (float4 loads) ----------------
__global__ __launch_bounds__(256) void k_fn(
    const float* __restrict__ AGG, const float* __restrict__ x,
    const float* __restrict__ fWT,
    const float* __restrict__ b0, const float* __restrict__ b1, const float* __restrict__ b2,
    float* __restrict__ out)
{
    __shared__ float in96T[96][8];
    __shared__ float h1T[128][8];
    __shared__ float h2T[128][8];
    const int t = threadIdx.x;
    const int half = t >> 7, f = t & 127;
    const int node0 = blockIdx.x * 8;
    const float* fW0T = fWT;            // [128][96]
    const float* fW1T = fWT + 12288;    // [128][128]
    const float* fW2T = fW1T + 16384;   // [32][128]

    for (int idx = t; idx < 768; idx += 256) {
        int nn = idx & 7, k = idx >> 3;
        in96T[k][nn] = (k < 64) ? AGG[(node0 + nn) * 64 + k]
                                : x[(node0 + nn) * 32 + (k - 64)];
    }
    __syncthreads();

    // layer 1: 96 -> 128, weights contiguous per output feature (24 float4 loads)
    {
        const float4* wr = (const float4*)(fW0T + f * 96);
        float a0 = b0[f], a1 = a0, a2 = a0, a3 = a0;
#pragma unroll 6
        for (int kk = 0; kk < 24; ++kk) {
            const float4 wv = wr[kk];
#pragma unroll
            for (int j = 0; j < 4; ++j) {
                const float wj = j == 0 ? wv.x : j == 1 ? wv.y : j == 2 ? wv.z : wv.w;
                const float4 iv = *(const float4*)(&in96T[4 * kk + j][4 * half]);
                a0 += iv.x * wj; a1 += iv.y * wj; a2 += iv.z * wj; a3 += iv.w * wj;
            }
        }
        float4 o = {lrel(a0), lrel(a1), lrel(a2), lrel(a3)};
        *(float4*)(&h1T[f][4 * half]) = o;
    }
    __syncthreads();

    // layer 2: 128 -> 128 (32 float4 weight loads)
    {
        const float4* wr = (const float4*)(fW1T + f * 128);
        float a0 = b1[f], a1 = a0, a2 = a0, a3 = a0;
#pragma unroll 8
        for (int kk = 0; kk < 32; ++kk) {
            const float4 wv = wr[kk];
#pragma unroll
            for (int j = 0; j < 4; ++j) {
                const float wj = j == 0 ? wv.x : j == 1 ? wv.y : j == 2 ? wv.z : wv.w;
                const float4 iv = *(const float4*)(&h1T[4 * kk + j][4 * half]);
                a0 += iv.x * wj; a1 += iv.y * wj; a2 += iv.z * wj; a3 += iv.w * wj;
            }
        }
        float4 o = {lrel(a0), lrel(a1), lrel(a2), lrel(a3)};
        *(float4*)(&h2T[f][4 * half]) = o;
    }
    __syncthreads();

    // layer 3: 128 -> 32 (linear; 32 float4 weight loads)
    {
        const int nn = t >> 5, fo = t & 31;
        const float4* wr = (const float4*)(fW2T + fo * 128);
        float a = b2[fo];
#pragma unroll 8
        for (int kk = 0; kk < 32; ++kk) {
            const float4 wv = wr[kk];
            a += h2T[4 * kk + 0][nn] * wv.x;
            a += h2T[4 * kk + 1][nn] * wv.y;
            a += h2T[4 * kk + 2][nn] * wv.z;
            a += h2T[4 * kk + 3][nn] * wv.w;
        }
        out[(node0 + nn) * 32 + fo] = a;
    }
}

extern "C" void kernel_launch(void* const* d_in, const int* in_sizes, int n_in,
                              void* d_out, int out_size, void* d_ws, size_t ws_size,
                              hipStream_t stream)
{
    const float* x    = (const float*)d_in[0];
    const float* feW0 = (const float*)d_in[1];
    const float* feb0 = (const float*)d_in[2];
    const float* feW1 = (const float*)d_in[3];
    const float* feb1 = (const float*)d_in[4];
    const float* feW2 = (const float*)d_in[5];
    const float* feb2 = (const float*)d_in[6];
    const float* fnW0 = (const float*)d_in[7];
    const float* fnb0 = (const float*)d_in[8];
    const float* fnW1 = (const float*)d_in[9];
    const float* fnb1 = (const float*)d_in[10];
    const float* fnW2 = (const float*)d_in[11];
    const float* fnb2 = (const float*)d_in[12];
    float* out = (float*)d_out;

    // workspace: Upi (1MB) | AGG (1MB) | xbf (256KB) | WF (20KB) | fWT (128KB)
    float* Upi = (float*)d_ws;
    float* AGG = Upi + 262144;
    unsigned short* xbf = (unsigned short*)(AGG + 262144);
    unsigned int* WF = (unsigned int*)(xbf + 131072);
    float* fWT = (float*)(WF + 5120);

    hipLaunchKernelGGL(k_uv,   dim3(1026), dim3(256), 0, stream,
                       x, feW0, feb0, feW1, feW2, fnW0, fnW1, fnW2, Upi, xbf, WF, fWT);
    hipLaunchKernelGGL(k_edge, dim3(1024), dim3(256), 0, stream, Upi, xbf, WF, feb1, feb2, AGG);
    hipLaunchKernelGGL(k_fn,   dim3(512),  dim3(256), 0, stream, AGG, x, fWT, fnb0, fnb1, fnb2, out);
}

// Round 23
// 73.537 us; speedup vs baseline: 1.3072x; 1.3072x over previous
//
#include <hip/hip_runtime.h>
#include <hip/hip_bf16.h>

#define ALPHA 0.2f
static __device__ __forceinline__ float lrel(float x) { return fmaxf(x, ALPHA * x); }

typedef __attribute__((ext_vector_type(8))) short bf16x8;
typedef __attribute__((ext_vector_type(4))) float f32x4;

union FragU { bf16x8 v; unsigned int u[4]; uint4 q; };

// VGPR-form MFMA via inline asm ("v" pins operands to arch VGPRs)
static __device__ __forceinline__ f32x4 mfma_init(bf16x8 a, bf16x8 b, f32x4 c) {
    f32x4 d;
    asm("v_mfma_f32_16x16x32_bf16 %0, %1, %2, %3" : "=&v"(d) : "v"(a), "v"(b), "v"(c));
    return d;
}
static __device__ __forceinline__ void mfma_acc(f32x4& acc, bf16x8 a, bf16x8 b) {
    asm("v_mfma_f32_16x16x32_bf16 %0, %1, %2, %0" : "+v"(acc) : "v"(a), "v"(b));
}

// pack two f32 -> one dword of 2 bf16 (RNE)
static __device__ __forceinline__ unsigned int pk2(float a, float b) {
    unsigned int r;
    asm("v_cvt_pk_bf16_f32 %0, %1, %2" : "=v"(r) : "v"(a), "v"(b));
    return r;
}
static __device__ __forceinline__ unsigned int cvl2(float a, float b) {
    return pk2(lrel(a), lrel(b));
}
// a += |x|  (VOP3 abs input modifier: single v_add)
static __device__ __forceinline__ void addabs(float& a, float x) {
    asm("v_add_f32 %0, %0, |%1|" : "+v"(a) : "v"(x));
}
// f32 -> bf16 (RNE) scalar
static __device__ __forceinline__ unsigned short f2bf(float x) {
    union { float f; unsigned int u; } c;
    c.f = x;
    unsigned int r = c.u + 0x7FFFu + ((c.u >> 16) & 1u);
    return (unsigned short)(r >> 16);
}
// pi permutation on 64 features: slot(16nf+4a+r) -> 32(nf>>1)+8a+4(nf&1)+r
static __device__ __forceinline__ int pi64(int s) {
    return 32 * ((s >> 4) >> 1) + 8 * ((s >> 2) & 3) + 4 * ((s >> 4) & 1) + (s & 3);
}

// ---------------- Kernel 1: Upi = pi(x @ W0top + b0), x_bf, weight fragments ----------------
__global__ __launch_bounds__(256) void k_uv(
    const float* __restrict__ x, const float* __restrict__ W0, const float* __restrict__ b0,
    const float* __restrict__ W1, const float* __restrict__ W2,
    float* __restrict__ Upi, unsigned short* __restrict__ xbf, unsigned int* __restrict__ WF)
{
    if (blockIdx.x == 1024) {
        const int t = threadIdx.x;
        const int l = t & 63, part = t >> 6;
        const int lo = l & 15, g = l >> 4;
        for (int ff = part; ff < 20; ff += 4) {
            unsigned int o[4];
            if (ff < 4) {
                const int nf = ff;
                const int pc = 32 * (nf >> 1) + 8 * (lo >> 2) + 4 * (nf & 1) + (lo & 3);
#pragma unroll
                for (int uq = 0; uq < 4; ++uq) {
                    const int k0 = 8 * g + 2 * uq;
                    o[uq] = pk2(W0[(32 + k0) * 64 + pc], W0[(33 + k0) * 64 + pc]);
                }
            } else if (ff < 12) {
                const int s = (ff - 4) >> 2, nf = (ff - 4) & 3;
                const int pc = 32 * (nf >> 1) + 8 * (lo >> 2) + 4 * (nf & 1) + (lo & 3);
#pragma unroll
                for (int uq = 0; uq < 4; ++uq) {
                    const int k0 = 32 * s + 8 * g + 2 * uq;
                    o[uq] = pk2(W1[k0 * 64 + pc], W1[(k0 + 1) * 64 + pc]);
                }
            } else {
                const int s = (ff - 12) >> 2, nf = (ff - 12) & 3;
                const int c2 = 16 * nf + lo;
#pragma unroll
                for (int uq = 0; uq < 4; ++uq) {
                    const int k0 = 32 * s + 8 * g + 2 * uq;
                    o[uq] = pk2(W2[k0 * 64 + c2], W2[(k0 + 1) * 64 + c2]);
                }
            }
            *(uint4*)(WF + (ff * 64 + l) * 4) = make_uint4(o[0], o[1], o[2], o[3]);
        }
        return;
    }
    const int idx = blockIdx.x * 256 + threadIdx.x;
    const int n = idx >> 6;
    const int slot = idx & 63;
    const int f = pi64(slot);
    const float* xr = x + n * 32;
    float u = b0[f];
#pragma unroll
    for (int i = 0; i < 32; ++i) u += xr[i] * W0[i * 64 + f];
    Upi[idx] = u;
    if (slot < 32) xbf[n * 32 + slot] = f2bf(xr[slot]);
}

// ---------------- Kernel 2: edge MLP (all 3 layers on MFMA) + sum over j ----------------
// R11 structure (skewed pipeline, W1 from LDS, W0/W2 in regs) with ALL MFMAs in
// VGPR-form via inline asm. Best measured configuration (k_edge ~63.2 us).
__global__ __launch_bounds__(256, 2) void k_edge(
    const float* __restrict__ Upi, const unsigned short* __restrict__ xbf,
    const unsigned int* __restrict__ WF,
    const float* __restrict__ b1, const float* __restrict__ b2,
    float* __restrict__ AGG)
{
    __shared__ uint4 wlds[512];  // w1f frags only: [0..7] = (s*4+nf)
    const int tid = threadIdx.x;
    const int w = tid >> 6, l = tid & 63;
    const int lo = l & 15, g = l >> 4;
    const int bid = blockIdx.x;
    const int b = bid >> 7, ig = bid & 127;
    const int node = b * 512 + ig * 4 + w;

    // ---- stage W1 fragments into LDS (once per block)
    for (int idx = tid; idx < 512; idx += 256)
        wlds[idx] = ((const uint4*)WF)[256 + idx];

    // ---- W0bot + W2 fragments in registers
    FragU w0f[4], w2f[2][4];
    const uint4* wp = (const uint4*)WF;
#pragma unroll
    for (int nf = 0; nf < 4; ++nf) w0f[nf].q = wp[nf * 64 + l];
#pragma unroll
    for (int s = 0; s < 2; ++s)
#pragma unroll
        for (int nf = 0; nf < 4; ++nf) w2f[s][nf].q = wp[(12 + s * 4 + nf) * 64 + l];

    // ---- per-i C-init for GEMM0 (Upi broadcast) + bias C-inits
    f32x4 u0f[4], b1f[4], b2f[4];
#pragma unroll
    for (int nf = 0; nf < 4; ++nf) {
        const float4 t0 = *(const float4*)(Upi + node * 64 + nf * 16 + 4 * g);
        u0f[nf] = (f32x4){t0.x, t0.y, t0.z, t0.w};
        const float4 t1 = *(const float4*)(b1 + 32 * (nf >> 1) + 8 * g + 4 * (nf & 1));
        const float4 t2 = *(const float4*)(b2 + 16 * nf + 4 * g);
        b1f[nf] = (f32x4){t1.x, t1.y, t1.z, t1.w};
        b2f[nf] = (f32x4){t2.x, t2.y, t2.z, t2.w};
    }

    const unsigned short* xb = xbf + b * 512 * 32;

    // ---- prologue: xj frags for tiles 0,1; GEMM0 for tile 0
    FragU xjT0, xjB;
    xjT0.q = *(const uint4*)(xb + lo * 32 + 8 * g);         // tile 0
    xjB.q  = *(const uint4*)(xb + (16 + lo) * 32 + 8 * g);  // tile 1

    __syncthreads();

    f32x4 acc0c[4];
#pragma unroll
    for (int nf = 0; nf < 4; ++nf)
        acc0c[nf] = mfma_init(w0f[nf].v, xjT0.v, u0f[nf]);

    f32x4 acc2p[4];
#pragma unroll
    for (int nf = 0; nf < 4; ++nf) { f32x4 z = {0.f, 0.f, 0.f, 0.f}; acc2p[nf] = z; }

    float aggL[4][4], aggA[4][4];
#pragma unroll
    for (int nf = 0; nf < 4; ++nf)
#pragma unroll
        for (int r = 0; r < 4; ++r) { aggL[nf][r] = 0.f; aggA[nf][r] = 0.f; }

#pragma unroll 2
    for (int k = 0; k < 32; ++k) {
        // opaque zero: defeats LICM on the LDS weight reads
        int widx = 0;
        asm volatile("" : "+v"(widx));

        // load xj for tile k+2 (wraps; garbage tile never aggregated)
        const int jn = ((k + 2) & 31) * 16;
        FragU xjn;
        xjn.q = *(const uint4*)(xb + (jn + lo) * 32 + 8 * g);

        // ---- GEMM0 for tile k+1 (skewed one tile ahead)
        __builtin_amdgcn_s_setprio(1);
        f32x4 acc0n[4];
#pragma unroll
        for (int nf = 0; nf < 4; ++nf)
            acc0n[nf] = mfma_init(w0f[nf].v, xjB.v, u0f[nf]);
        __builtin_amdgcn_s_setprio(0);

        // ---- pack q from tile k's acc0 (overlaps GEMM0 MFMAs)
        FragU q0, q1;
        q0.u[0] = cvl2(acc0c[0][0], acc0c[0][1]);
        q0.u[1] = cvl2(acc0c[0][2], acc0c[0][3]);
        q0.u[2] = cvl2(acc0c[1][0], acc0c[1][1]);
        q0.u[3] = cvl2(acc0c[1][2], acc0c[1][3]);
        q1.u[0] = cvl2(acc0c[2][0], acc0c[2][1]);
        q1.u[1] = cvl2(acc0c[2][2], acc0c[2][3]);
        q1.u[2] = cvl2(acc0c[3][0], acc0c[3][1]);
        q1.u[3] = cvl2(acc0c[3][2], acc0c[3][3]);

        // ---- GEMM1 (W1 from LDS, bias C-init)
        __builtin_amdgcn_s_setprio(1);
        f32x4 acc1[4];
#pragma unroll
        for (int nf = 0; nf < 4; ++nf) {
            FragU wa, wb;
            wa.q = wlds[widx + nf * 64 + l];
            wb.q = wlds[widx + (4 + nf) * 64 + l];
            acc1[nf] = mfma_init(wa.v, q0.v, b1f[nf]);
            mfma_acc(acc1[nf], wb.v, q1.v);
        }
        __builtin_amdgcn_s_setprio(0);

        // ---- agg of PREVIOUS tile's acc2 (overlaps GEMM1 MFMAs)
#pragma unroll
        for (int nf = 0; nf < 4; ++nf)
#pragma unroll
            for (int r = 0; r < 4; ++r) {
                aggL[nf][r] += acc2p[nf][r];
                addabs(aggA[nf][r], acc2p[nf][r]);
            }

        // ---- pack p from acc1 (pi trick: regs are GEMM2's B-fragment)
        FragU p0, p1;
        p0.u[0] = cvl2(acc1[0][0], acc1[0][1]);
        p0.u[1] = cvl2(acc1[0][2], acc1[0][3]);
        p0.u[2] = cvl2(acc1[1][0], acc1[1][1]);
        p0.u[3] = cvl2(acc1[1][2], acc1[1][3]);
        p1.u[0] = cvl2(acc1[2][0], acc1[2][1]);
        p1.u[1] = cvl2(acc1[2][2], acc1[2][3]);
        p1.u[2] = cvl2(acc1[3][0], acc1[3][1]);
        p1.u[3] = cvl2(acc1[3][2], acc1[3][3]);

        // ---- GEMM2 (W2 in regs, bias C-init) -> becomes "previous" for next iter
        __builtin_amdgcn_s_setprio(1);
#pragma unroll
        for (int nf = 0; nf < 4; ++nf) {
            acc2p[nf] = mfma_init(w2f[0][nf].v, p0.v, b2f[nf]);
            mfma_acc(acc2p[nf], w2f[1][nf].v, p1.v);
        }
        __builtin_amdgcn_s_setprio(0);

        // ---- rotate skew buffers (unroll-2 ping-pongs, no copies)
#pragma unroll
        for (int nf = 0; nf < 4; ++nf) acc0c[nf] = acc0n[nf];
        xjB = xjn;
    }

    // ---- epilogue: agg the last tile's acc2
#pragma unroll
    for (int nf = 0; nf < 4; ++nf)
#pragma unroll
        for (int r = 0; r < 4; ++r) {
            aggL[nf][r] += acc2p[nf][r];
            addabs(aggA[nf][r], acc2p[nf][r]);
        }

    // ---- combine lrel parts, reduce over the 16 edge-lanes, store
#pragma unroll
    for (int nf = 0; nf < 4; ++nf)
#pragma unroll
        for (int r = 0; r < 4; ++r) {
            float v = 0.6f * aggL[nf][r] + 0.4f * aggA[nf][r];
            v += __shfl_xor(v, 1);
            v += __shfl_xor(v, 2);
            v += __shfl_xor(v, 4);
            v += __shfl_xor(v, 8);
            aggL[nf][r] = v;
        }
    if (lo == 0) {
#pragma unroll
        for (int nf = 0; nf < 4; ++nf) {
            float4 o = {aggL[nf][0], aggL[nf][1], aggL[nf][2], aggL[nf][3]};
            *(float4*)(AGG + node * 64 + 16 * nf + 4 * g) = o;
        }
    }
}

// ---------------- Kernel 3: node MLP fn: [agg, x] -> 128 -> 128 -> 32 ----------------
// NOTE: thread f reading W[k*128+f] is cross-lane coalesced (64 lanes -> 256B/txn);
// do NOT "vectorize" per-thread (R22 regression: per-lane rows broke coalescing).
__global__ __launch_bounds__(256) void k_fn(
    const float* __restrict__ AGG, const float* __restrict__ x,
    const float* __restrict__ W0, const float* __restrict__ b0,
    const float* __restrict__ W1, const float* __restrict__ b1,
    const float* __restrict__ W2, const float* __restrict__ b2,
    float* __restrict__ out)
{
    __shared__ float in96T[96][8];
    __shared__ float h1T[128][8];
    __shared__ float h2T[128][8];
    const int t = threadIdx.x;
    const int half = t >> 7, f = t & 127;
    const int node0 = blockIdx.x * 8;

    for (int idx = t; idx < 768; idx += 256) {
        int nn = idx & 7, k = idx >> 3;
        in96T[k][nn] = (k < 64) ? AGG[(node0 + nn) * 64 + k]
                                : x[(node0 + nn) * 32 + (k - 64)];
    }
    __syncthreads();

    {
        float a0 = b0[f], a1 = a0, a2 = a0, a3 = a0;
#pragma unroll 4
        for (int k = 0; k < 96; ++k) {
            const float4 iv = *(const float4*)(&in96T[k][4 * half]);
            const float wv = W0[k * 128 + f];
            a0 += iv.x * wv; a1 += iv.y * wv; a2 += iv.z * wv; a3 += iv.w * wv;
        }
        float4 o = {lrel(a0), lrel(a1), lrel(a2), lrel(a3)};
        *(float4*)(&h1T[f][4 * half]) = o;
    }
    __syncthreads();

    {
        float a0 = b1[f], a1 = a0, a2 = a0, a3 = a0;
#pragma unroll 4
        for (int k = 0; k < 128; ++k) {
            const float4 iv = *(const float4*)(&h1T[k][4 * half]);
            const float wv = W1[k * 128 + f];
            a0 += iv.x * wv; a1 += iv.y * wv; a2 += iv.z * wv; a3 += iv.w * wv;
        }
        float4 o = {lrel(a0), lrel(a1), lrel(a2), lrel(a3)};
        *(float4*)(&h2T[f][4 * half]) = o;
    }
    __syncthreads();

    {
        const int nn = t >> 5, fo = t & 31;
        float a = b2[fo];
#pragma unroll 4
        for (int k = 0; k < 128; ++k) a += h2T[k][nn] * W2[k * 32 + fo];
        out[(node0 + nn) * 32 + fo] = a;
    }
}

extern "C" void kernel_launch(void* const* d_in, const int* in_sizes, int n_in,
                              void* d_out, int out_size, void* d_ws, size_t ws_size,
                              hipStream_t stream)
{
    const float* x    = (const float*)d_in[0];
    const float* feW0 = (const float*)d_in[1];
    const float* feb0 = (const float*)d_in[2];
    const float* feW1 = (const float*)d_in[3];
    const float* feb1 = (const float*)d_in[4];
    const float* feW2 = (const float*)d_in[5];
    const float* feb2 = (const float*)d_in[6];
    const float* fnW0 = (const float*)d_in[7];
    const float* fnb0 = (const float*)d_in[8];
    const float* fnW1 = (const float*)d_in[9];
    const float* fnb1 = (const float*)d_in[10];
    const float* fnW2 = (const float*)d_in[11];
    const float* fnb2 = (const float*)d_in[12];
    float* out = (float*)d_out;

    // workspace: Upi (1MB) | AGG (1MB) | xbf (256KB) | WF (20KB)
    float* Upi = (float*)d_ws;
    float* AGG = Upi + 262144;
    unsigned short* xbf = (unsigned short*)(AGG + 262144);
    unsigned int* WF = (unsigned int*)(xbf + 131072);

    hipLaunchKernelGGL(k_uv,   dim3(1025), dim3(256), 0, stream, x, feW0, feb0, feW1, feW2, Upi, xbf, WF);
    hipLaunchKernelGGL(k_edge, dim3(1024), dim3(256), 0, stream, Upi, xbf, WF, feb1, feb2, AGG);
    hipLaunchKernelGGL(k_fn,   dim3(512),  dim3(256), 0, stream, AGG, x, fnW0, fnb0, fnW1, fnb1, fnW2, fnb2, out);
}